// Round 14
// baseline (30657.364 us; speedup 1.0000x reference)
//
#include <hip/hip_runtime.h>

// Problem dims
#define Bn   64
#define Sn   512
#define Dn   768
#define Hn   384
#define G4n  1536   // 4*H
#define Tn   9
#define SCHn 64     // S-chunk
#define NCH  8      // Sn / SCHn

// gates buffer: [dir][b][j][1536] bf16 for one (layer,chunk); 4 buffers (layer x parity)
#define BUFU (2ull * Bn * SCHn * G4n)                     // ushorts per buffer

// ---- workspace layout (in float units) ----
#define OFF_WIHB  0ull
#define SZ_WIHB   (2ull * Dn * G4n)
#define OFF_WHHB  (OFF_WIHB + SZ_WIHB)
#define SZ_WHHB   (2ull * Hn * G4n)                       // 4x[1536][384] bf16
#define OFF_GATESB (OFF_WHHB + SZ_WHHB)
#define SZ_GATESB (4ull * BUFU / 2)
#define OFF_H1B   (OFF_GATESB + SZ_GATESB)
#define SZ_H1B    ((unsigned long long)Bn * Sn * Dn / 2)
#define OFF_BERTB (OFF_H1B + SZ_H1B)
#define SZ_BERTB  ((unsigned long long)Bn * Sn * Dn / 2)
#define OFF_EMP   (OFF_BERTB + SZ_BERTB)
#define SZ_EMP    (2ull * Bn * Sn * Tn)
#define OFF_EM    (OFF_EMP + SZ_EMP)
#define SZ_EM     ((unsigned long long)Bn * Sn * Tn)
#define OFF_HBUF  (OFF_EM + SZ_EM)
#define SZ_HBUF   (8ull * Bn * Hn)                        // [L][parity][dir][b][d]
#define OFF_CST   (OFF_HBUF + SZ_HBUF)
#define SZ_CST    (4ull * Bn * Hn)                        // [L][dir][b][d]
#define OFF_LP    (OFF_CST + SZ_CST)
#define SZ_LP     64ull
#define OFF_STAMP (OFF_LP + SZ_LP)
// stamps: [L:2][dir:2][bg:8][dg:32] lines of 32 ints; tag = sg+1 (per-layer region)
#define STAMP_TOTAL (2 * 2 * 8 * 32 * 32)

typedef __attribute__((ext_vector_type(8))) short short8v;
typedef __attribute__((ext_vector_type(4))) float f32x4;

static __device__ __forceinline__ float sigf(float x) { return 1.f / (1.f + expf(-x)); }

static __device__ __forceinline__ unsigned short f2bf(float x) {
    unsigned u = __float_as_uint(x);
    u += 0x7fffu + ((u >> 16) & 1u);   // RNE
    return (unsigned short)(u >> 16);
}
static __device__ __forceinline__ float bf2f(unsigned short u) {
    return __uint_as_float(((unsigned)u) << 16);
}
static __device__ __forceinline__ float bflo(unsigned u) {
    return __uint_as_float(u << 16);
}
static __device__ __forceinline__ float bfhi(unsigned u) {
    return __uint_as_float(u & 0xffff0000u);
}

// ---- LLC primitives: relaxed system scope ----
static __device__ __forceinline__ unsigned long long llc_load_u64(const unsigned long long* p) {
    return __hip_atomic_load(p, __ATOMIC_RELAXED, __HIP_MEMORY_SCOPE_SYSTEM);
}
static __device__ __forceinline__ void llc_store_f32(float* p, float v) {
    __hip_atomic_store(p, v, __ATOMIC_RELAXED, __HIP_MEMORY_SCOPE_SYSTEM);
}
static __device__ __forceinline__ int llc_load_i32(const int* p) {
    return __hip_atomic_load(p, __ATOMIC_RELAXED, __HIP_MEMORY_SCOPE_SYSTEM);
}

// ---------------- fp32 -> bf16 convert ----------------
__global__ void to_bf16(const float* __restrict__ in, unsigned short* __restrict__ out,
                        int total)
{
    for (int i = blockIdx.x * 256 + threadIdx.x; i < total; i += gridDim.x * 256)
        out[i] = f2bf(in[i]);
}

// ---------------- stamp init (every launch: replay-safe) ----------------
__global__ void init_bar(int* __restrict__ st)
{
    const int i = blockIdx.x * 256 + threadIdx.x;
    if (i < STAMP_TOTAL) st[i] = 0;
}

// ---------------- gemm tile body (bf16 in/out, MFMA) ----------------
static __device__ __forceinline__ void gemm_tile(
    unsigned short As[][40], unsigned short Bs[][40],
    const unsigned short* __restrict__ Abf,
    const unsigned short* __restrict__ Wb,
    const float* __restrict__ bvec,
    unsigned short* __restrict__ G,
    int layer, int chunk, int nb, int mb, int tid)
{
    const int m0  = mb * 128;
    const int dir = mb >> 5;          // 32 tiles (4096 rows) per dir
    const int n0c = nb * 128;

    const unsigned short* BT = Wb + (size_t)(layer * 2 + dir) * G4n * Dn;
    const float* bias = bvec + (size_t)(layer * 2 + dir) * G4n;

    const int mm   = tid >> 1;
    const int seg  = (tid & 1) * 16;
    const int rem  = (m0 + mm) & (Bn * SCHn - 1);
    const int bb   = rem >> 6;
    const int j    = rem & (SCHn - 1);
    const int p    = chunk * SCHn + j;
    const int s    = dir ? (Sn - 1 - p) : p;
    const unsigned short* arow = Abf + ((size_t)bb * Sn + s) * Dn;
    const unsigned short* brow = BT + (size_t)(n0c + mm) * Dn;

    const int l = tid & 63, wave = tid >> 6;
    const int wy = wave >> 1, wx = wave & 1;
    const int fr = l & 15, fk = (l >> 4) * 8;

    f32x4 acc[4][4];
    #pragma unroll
    for (int mt = 0; mt < 4; ++mt)
        #pragma unroll
        for (int nt = 0; nt < 4; ++nt)
            acc[mt][nt] = (f32x4){0.f, 0.f, 0.f, 0.f};

    for (int k0 = 0; k0 < Dn; k0 += 32) {
        const short8v a0 = *(const short8v*)(arow + k0 + seg);
        const short8v a1 = *(const short8v*)(arow + k0 + seg + 8);
        const short8v b0 = *(const short8v*)(brow + k0 + seg);
        const short8v b1 = *(const short8v*)(brow + k0 + seg + 8);
        __syncthreads();
        *(short8v*)&As[mm][seg]     = a0;
        *(short8v*)&As[mm][seg + 8] = a1;
        *(short8v*)&Bs[mm][seg]     = b0;
        *(short8v*)&Bs[mm][seg + 8] = b1;
        __syncthreads();

        short8v af[4], bf[4];
        #pragma unroll
        for (int mt = 0; mt < 4; ++mt)
            af[mt] = *(const short8v*)&As[wy * 64 + mt * 16 + fr][fk];
        #pragma unroll
        for (int nt = 0; nt < 4; ++nt)
            bf[nt] = *(const short8v*)&Bs[wx * 64 + nt * 16 + fr][fk];
        #pragma unroll
        for (int mt = 0; mt < 4; ++mt)
            #pragma unroll
            for (int nt = 0; nt < 4; ++nt)
                acc[mt][nt] = __builtin_amdgcn_mfma_f32_16x16x32_bf16(
                    af[mt], bf[nt], acc[mt][nt], 0, 0, 0);
    }

    #pragma unroll
    for (int nt = 0; nt < 4; ++nt) {
        const int n  = n0c + wx * 64 + nt * 16 + fr;
        const int g  = n / 384;
        const int d2 = n - g * 384;
        const int gcol = d2 * 4 + g;
        const float bv = bias[n];
        #pragma unroll
        for (int mt = 0; mt < 4; ++mt) {
            #pragma unroll
            for (int q = 0; q < 4; ++q) {
                const int row = m0 + wy * 64 + mt * 16 + (l >> 4) * 4 + q;
                G[(size_t)row * G4n + gcol] = f2bf(acc[mt][nt][q] + bv);
            }
        }
    }
}

// ---------------- paired gates GEMM ----------------
__global__ __launch_bounds__(256) void gemm_pair(
    const unsigned short* __restrict__ A0, int l0, int c0, unsigned short* __restrict__ G0,
    const unsigned short* __restrict__ A1, int l1, int c1, unsigned short* __restrict__ G1,
    int valid1,
    const unsigned short* __restrict__ Wb, const float* __restrict__ bvec)
{
    __shared__ __align__(16) unsigned short As[128][40];
    __shared__ __align__(16) unsigned short Bs[128][40];
    if (blockIdx.z == 1) {
        if (!valid1) return;
        gemm_tile(As, Bs, A1, Wb, bvec, G1, l1, c1, blockIdx.x, blockIdx.y, threadIdx.x);
    } else {
        gemm_tile(As, Bs, A0, Wb, bvec, G0, l0, c0, blockIdx.x, blockIdx.y, threadIdx.x);
    }
}

// ---------------- wave-split dual-layer persistent LSTM ----------------
// grid 512 = (dir:2) x (bg:8 of 8 batches) x (dg:32 of 12 dims); 2 WGs/CU.
// Waves 0-1 = task A (layer la), waves 2-3 = task B (layer lb). Both chains'
// LLC stalls overlap on the same CU deterministically. Whh held as bf16 pairs
// (72 dwords/thread). Barriers are WG-wide; invalid tasks run fully predicated.
__global__ __launch_bounds__(256, 2) void lstm_dual(
    const unsigned short* __restrict__ grdA, int la, int ca,
    const unsigned short* __restrict__ grdB, int lb, int cb, int validB,
    const unsigned short* __restrict__ Whhb,  // [2][2][1536][384] bf16
    const float* __restrict__ fcw,            // [9][768]
    unsigned short* __restrict__ h1b,         // [64][512][768] bf16 (layer 0)
    float* __restrict__ emP,                  // [2][64][512][9] (layer 1)
    float* __restrict__ hbuf,                 // [L][parity][dir][64][384]
    float* __restrict__ cst,                  // [L][dir][64][384]
    int* __restrict__ stamps)
{
    const int tid = threadIdx.x;
    const int bid = blockIdx.x;
    const int dir = bid >> 8;
    const int bg  = (bid >> 5) & 7;
    const int dg  = bid & 31;
    const int b0 = bg * 8, d0 = dg * 12;

    const int T = tid >> 7;            // task id
    const int t = tid & 127;           // task-local tid
    const int valid = T ? validB : 1;
    const int layer = T ? lb : la;
    const int chunk = T ? cb : ca;
    const unsigned short* grd = T ? grdB : grdA;

    __shared__ __align__(16) float hstage[2][8][396];
    __shared__ __align__(16) float red[2][2][16][28];
    __shared__ float cs[2][8][12];
    __shared__ float fcwl[2][Hn];

    const int ct = t & 15;             // matvec col-group (3 cols)
    const int kq = t >> 4;             // matvec k-slice (48)
    const int k0 = kq * 48;
    const int sbb = t >> 4;            // staging/FC batch (0..7)
    const int skq = t & 15;            // staging/FC dim-slice (24 dims)
    const bool pw = (t < 96);
    const int pb = t / 12, pdd = t - pb * 12;
    const int w = (t >> 6) & 1;        // wave within task

    int* lstamps = stamps + layer * (2 * 8 * 32 * 32);
    const int* sp0 = lstamps + ((dir * 8 + bg) * 32 + 2 * skq) * 32;
    const int* sp1 = sp0 + 32;
    float* lhbuf = hbuf + (size_t)layer * (4ull * Bn * Hn);
    float* lcst  = cst + (size_t)layer * (2ull * Bn * Hn);

    // ---- Whh slice into registers (bf16 pairs: 3 cols x 48 k = 72 dwords) ----
    unsigned wregp[72];
    if (valid) {
        const unsigned short* Wbase = Whhb + (size_t)(layer * 2 + dir) * G4n * Hn;
        #pragma unroll
        for (int c = 0; c < 3; ++c) {
            const int cc = ct * 3 + c;               // col' = dd*4+g
            const int dd = cc >> 2, g = cc & 3;
            const uint4* wr = (const uint4*)(Wbase + (size_t)(g * Hn + d0 + dd) * Hn + k0);
            #pragma unroll
            for (int q = 0; q < 6; ++q) {
                const uint4 v = wr[q];
                wregp[c * 24 + q * 4 + 0] = v.x;
                wregp[c * 24 + q * 4 + 1] = v.y;
                wregp[c * 24 + q * 4 + 2] = v.z;
                wregp[c * 24 + q * 4 + 3] = v.w;
            }
        }
    }

    const bool fcwg = valid && (layer == 1) && (dg < Tn);
    if (fcwg) {
        for (int k2 = t; k2 < Hn; k2 += 128)
            fcwl[T][k2] = fcw[dg * Dn + dir * Hn + k2];
    }
    if (valid && pw) {
        cs[T][pb][pdd] = (chunk == 0) ? 0.f
            : lcst[((size_t)dir * Bn + b0 + pb) * Hn + d0 + pdd];
    }
    __syncthreads();

    for (int j = 0; j < SCHn; ++j) {
        const int sg = chunk * SCHn + j;
        const int p_rd = sg & 1, p_wr = (sg + 1) & 1;
        const int s = dir ? (Sn - 1 - sg) : sg;

        float4 g4 = make_float4(0.f, 0.f, 0.f, 0.f);
        if (valid) {
            // input gates (bf16; latency hides under poll/stage)
            if (pw) {
                const ushort4 gu = *(const ushort4*)(grd +
                      (((size_t)(dir * Bn + b0 + pb) * SCHn + j) * G4n) + (d0 + pdd) * 4);
                g4.x = bf2f(gu.x); g4.y = bf2f(gu.y);
                g4.z = bf2f(gu.z); g4.w = bf2f(gu.w);
            }
            // poll 2 producer stamps + load 24 dims of batch sbb
            if (chunk == 0 && j == 0) {
                #pragma unroll
                for (int i = 0; i < 6; ++i)
                    *(float4*)&hstage[T][sbb][skq * 24 + 4 * i] =
                        make_float4(0.f, 0.f, 0.f, 0.f);
            } else {
                const int need = sg;
                while (llc_load_i32(sp0) < need || llc_load_i32(sp1) < need)
                    __builtin_amdgcn_s_sleep(1);
                const unsigned long long* hsrc = (const unsigned long long*)
                    (lhbuf + ((size_t)(p_rd * 2 + dir) * Bn + b0 + sbb) * Hn) + skq * 12;
                #pragma unroll
                for (int i = 0; i < 6; ++i) {
                    const unsigned long long v0 = llc_load_u64(hsrc + 2 * i);
                    const unsigned long long v1 = llc_load_u64(hsrc + 2 * i + 1);
                    float4 f;
                    f.x = __uint_as_float((unsigned)v0);
                    f.y = __uint_as_float((unsigned)(v0 >> 32));
                    f.z = __uint_as_float((unsigned)v1);
                    f.w = __uint_as_float((unsigned)(v1 >> 32));
                    *(float4*)&hstage[T][sbb][skq * 24 + 4 * i] = f;
                }
            }
        }
        __syncthreads();   // B: hstage ready

        if (valid) {
            // ---- recurrent matvec: 3 cols x 48 k x 8 batches ----
            float acc[24];
            #pragma unroll
            for (int i = 0; i < 24; ++i) acc[i] = 0.f;
            #pragma unroll
            for (int i = 0; i < 12; ++i) {
                float wf[12];
                #pragma unroll
                for (int c = 0; c < 3; ++c) {
                    const unsigned u0 = wregp[c * 24 + 2 * i];
                    const unsigned u1 = wregp[c * 24 + 2 * i + 1];
                    wf[c * 4 + 0] = bflo(u0); wf[c * 4 + 1] = bfhi(u0);
                    wf[c * 4 + 2] = bflo(u1); wf[c * 4 + 3] = bfhi(u1);
                }
                #pragma unroll
                for (int b = 0; b < 8; ++b) {
                    const float4 h4 = *(const float4*)&hstage[T][b][k0 + 4 * i];
                    acc[b * 3 + 0] += h4.x * wf[0] + h4.y * wf[1]
                                    + h4.z * wf[2] + h4.w * wf[3];
                    acc[b * 3 + 1] += h4.x * wf[4] + h4.y * wf[5]
                                    + h4.z * wf[6] + h4.w * wf[7];
                    acc[b * 3 + 2] += h4.x * wf[8] + h4.y * wf[9]
                                    + h4.z * wf[10] + h4.w * wf[11];
                }
            }
            // reduce 4 kq sub-slices within wave
            #pragma unroll
            for (int i = 0; i < 24; ++i) {
                acc[i] += __shfl_xor(acc[i], 16);
                acc[i] += __shfl_xor(acc[i], 32);
            }
            if ((t & 63) < 16) {
                #pragma unroll
                for (int i = 0; i < 24; i += 4) {
                    float4 t4; t4.x = acc[i]; t4.y = acc[i + 1];
                    t4.z = acc[i + 2]; t4.w = acc[i + 3];
                    *(float4*)&red[T][w][t & 15][i] = t4;
                }
            }
            // fused FC for step sg-1 (hstage holds its output h)
            if (fcwg && j >= 1) {
                const int sgp = sg - 1;
                const int sprev = dir ? (Sn - 1 - sgp) : sgp;
                const float* hp2 = &hstage[T][sbb][skq * 24];
                const float* wp2 = &fcwl[T][skq * 24];
                float e2 = 0.f;
                #pragma unroll
                for (int q = 0; q < 24; ++q) e2 += hp2[q] * wp2[q];
                e2 += __shfl_down(e2, 8, 16);
                e2 += __shfl_down(e2, 4, 16);
                e2 += __shfl_down(e2, 2, 16);
                e2 += __shfl_down(e2, 1, 16);
                if (skq == 0)
                    emP[((size_t)(dir * Bn + b0 + sbb) * Sn + sprev) * Tn + dg] = e2;
            }
        }
        __syncthreads();   // C: red ready, hstage readers done

        if (valid && pw) {
            float pre[4];
            #pragma unroll
            for (int g = 0; g < 4; ++g) {
                const int cc = pdd * 4 + g;
                const int ct2 = cc / 3;
                const int e = pb * 3 + (cc - ct2 * 3);
                pre[g] = red[T][0][ct2][e] + red[T][1][ct2][e];
            }
            const float ii = sigf(pre[0] + g4.x);
            const float ff = sigf(pre[1] + g4.y);
            const float gg = tanhf(pre[2] + g4.z);
            const float oo = sigf(pre[3] + g4.w);
            const float cn = ff * cs[T][pb][pdd] + ii * gg;
            cs[T][pb][pdd] = cn;
            const float hn = oo * tanhf(cn);
            llc_store_f32(&lhbuf[((size_t)(p_wr * 2 + dir) * Bn + b0 + pb) * Hn + d0 + pdd], hn);
            if (layer == 0)
                h1b[((size_t)(b0 + pb) * Sn + s) * Dn + dir * Hn + d0 + pdd] = f2bf(hn);
        }
        __syncthreads();   // D: all waves' stores drained (per-wave vmcnt before barrier)
        if (valid && t == 0)
            __hip_atomic_store(lstamps + ((dir * 8 + bg) * 32 + dg) * 32, sg + 1,
                               __ATOMIC_RELAXED, __HIP_MEMORY_SCOPE_SYSTEM);
    }

    // ---- epilogue: FC for this chunk's last step (barrier-free, reg-resident) ----
    if (fcwg) {
        const int sgl = chunk * SCHn + SCHn - 1;
        const int need = sgl + 1;
        const int pp = (sgl + 1) & 1;
        while (llc_load_i32(sp0) < need || llc_load_i32(sp1) < need)
            __builtin_amdgcn_s_sleep(1);
        const unsigned long long* hsrc = (const unsigned long long*)
            (lhbuf + ((size_t)(pp * 2 + dir) * Bn + b0 + sbb) * Hn) + skq * 12;
        float hv[24];
        #pragma unroll
        for (int i = 0; i < 12; ++i) {
            const unsigned long long v = llc_load_u64(hsrc + i);
            hv[2 * i]     = __uint_as_float((unsigned)v);
            hv[2 * i + 1] = __uint_as_float((unsigned)(v >> 32));
        }
        const float* wp2 = &fcwl[T][skq * 24];
        float e2 = 0.f;
        #pragma unroll
        for (int q = 0; q < 24; ++q) e2 += hv[q] * wp2[q];
        e2 += __shfl_down(e2, 8, 16);
        e2 += __shfl_down(e2, 4, 16);
        e2 += __shfl_down(e2, 2, 16);
        e2 += __shfl_down(e2, 1, 16);
        const int sprev = dir ? (Sn - 1 - sgl) : sgl;
        if (skq == 0)
            emP[((size_t)(dir * Bn + b0 + sbb) * Sn + sprev) * Tn + dg] = e2;
    }

    if (valid && pw)
        lcst[((size_t)dir * Bn + b0 + pb) * Hn + d0 + pdd] = cs[T][pb][pdd];
}

// ---------------- emission combine ----------------
__global__ void em_combine(const float* __restrict__ emP, const float* __restrict__ fcb,
                           float* __restrict__ em)
{
    const int idx = blockIdx.x * 256 + threadIdx.x;
    if (idx < Bn * Sn * Tn) {
        const int t = idx % Tn;
        em[idx] = emP[idx] + emP[(size_t)Bn * Sn * Tn + idx] + fcb[t];
    }
}

// ---------------- CRF negative log-likelihood ----------------
__global__ __launch_bounds__(64) void crf_loss(
    const float* __restrict__ em, const int* __restrict__ y,
    const float* __restrict__ trans, const float* __restrict__ start_t,
    const float* __restrict__ end_t, float* __restrict__ lossp)
{
    const int b = blockIdx.x, tid = threadIdx.x;
    __shared__ float tr[Tn * Tn];
    for (int i = tid; i < Tn * Tn; i += 64) tr[i] = trans[i];
    __syncthreads();
    const int* yb = y + (size_t)b * Sn;
    const float* emb = em + (size_t)b * Sn * Tn;

    float gs = 0.f;
    for (int s2 = tid; s2 < Sn; s2 += 64) gs += emb[s2 * Tn + yb[s2]];
    for (int s2 = tid; s2 < Sn - 1; s2 += 64) gs += tr[yb[s2] * Tn + yb[s2 + 1]];
    #pragma unroll
    for (int o = 32; o > 0; o >>= 1) gs += __shfl_down(gs, o, 64);

    const int jj = (tid < Tn) ? tid : 0;
    float alpha = start_t[jj] + emb[jj];
    for (int s2 = 1; s2 < Sn; ++s2) {
        float av[Tn];
        #pragma unroll
        for (int i = 0; i < Tn; ++i) av[i] = __shfl(alpha, i, 64) + tr[i * Tn + jj];
        float m = av[0];
        #pragma unroll
        for (int i = 1; i < Tn; ++i) m = fmaxf(m, av[i]);
        float ss = 0.f;
        #pragma unroll
        for (int i = 0; i < Tn; ++i) ss += expf(av[i] - m);
        alpha = logf(ss) + m + emb[s2 * Tn + jj];
    }
    const float xv = alpha + end_t[jj];
    float m9 = -1e30f, vv[Tn];
    #pragma unroll
    for (int i = 0; i < Tn; ++i) { vv[i] = __shfl(xv, i, 64); m9 = fmaxf(m9, vv[i]); }
    float s9 = 0.f;
    #pragma unroll
    for (int i = 0; i < Tn; ++i) s9 += expf(vv[i] - m9);
    const float logZ = logf(s9) + m9;
    if (tid == 0) lossp[b] = logZ - (gs + start_t[yb[0]] + end_t[yb[Sn - 1]]);
}

__global__ __launch_bounds__(64) void loss_final(const float* __restrict__ lossp,
                                                 float* __restrict__ out)
{
    float v = lossp[threadIdx.x];
    #pragma unroll
    for (int o = 32; o > 0; o >>= 1) v += __shfl_down(v, o, 64);
    if (threadIdx.x == 0) out[0] = v * (1.f / 64.f);
}

// ---------------- Viterbi decode ----------------
__global__ __launch_bounds__(64) void viterbi_k(
    const float* __restrict__ em, const float* __restrict__ trans,
    const float* __restrict__ start_t, const float* __restrict__ end_t,
    float* __restrict__ out)
{
    const int b = blockIdx.x, tid = threadIdx.x;
    __shared__ float tr[Tn * Tn];
    __shared__ unsigned char bp[Sn - 1][16];
    __shared__ float vfin[Tn];
    for (int i = tid; i < Tn * Tn; i += 64) tr[i] = trans[i];
    __syncthreads();
    const float* emb = em + (size_t)b * Sn * Tn;
    const int jj = (tid < Tn) ? tid : 0;
    float v = start_t[jj] + emb[jj];
    for (int s2 = 1; s2 < Sn; ++s2) {
        float vv[Tn];
        #pragma unroll
        for (int i = 0; i < Tn; ++i) vv[i] = __shfl(v, i, 64);
        float best = -1e30f; int bi = 0;
        #pragma unroll
        for (int i = 0; i < Tn; ++i) {
            const float sc = vv[i] + tr[i * Tn + jj];
            if (sc > best) { best = sc; bi = i; }   // strict > == first-max (np.argmax)
        }
        if (tid < Tn) bp[s2 - 1][tid] = (unsigned char)bi;
        v = best + emb[s2 * Tn + jj];
    }
    if (tid < Tn) vfin[tid] = v + end_t[tid];
    __syncthreads();
    if (tid == 0) {
        float best = -1e30f; int cur = 0;
        for (int i = 0; i < Tn; ++i) if (vfin[i] > best) { best = vfin[i]; cur = i; }
        float* ob = out + 1 + (size_t)b * Sn;
        ob[Sn - 1] = (float)cur;
        for (int s2 = Sn - 1; s2 >= 1; --s2) { cur = bp[s2 - 1][cur]; ob[s2 - 1] = (float)cur; }
    }
}

// ---------------- launch ----------------
extern "C" void kernel_launch(void* const* d_in, const int* in_sizes, int n_in,
                              void* d_out, int out_size, void* d_ws, size_t ws_size,
                              hipStream_t stream)
{
    (void)in_sizes; (void)n_in; (void)out_size; (void)ws_size;
    const float* bert  = (const float*)d_in[0];
    const int*   y     = (const int*)d_in[1];
    const float* Wih   = (const float*)d_in[2];
    const float* Whh   = (const float*)d_in[3];
    const float* bvec  = (const float*)d_in[4];
    const float* fcw   = (const float*)d_in[5];
    const float* fcb   = (const float*)d_in[6];
    const float* trans = (const float*)d_in[7];
    const float* stt   = (const float*)d_in[8];
    const float* ent   = (const float*)d_in[9];
    float* out = (float*)d_out;
    float* ws  = (float*)d_ws;

    unsigned short* Wihb   = (unsigned short*)(ws + OFF_WIHB);
    unsigned short* Whhb   = (unsigned short*)(ws + OFF_WHHB);
    unsigned short* gatesb = (unsigned short*)(ws + OFF_GATESB);
    unsigned short* h1b    = (unsigned short*)(ws + OFF_H1B);
    unsigned short* bertb  = (unsigned short*)(ws + OFF_BERTB);
    float* emP   = ws + OFF_EMP;
    float* em    = ws + OFF_EM;
    float* hbuf  = ws + OFF_HBUF;
    float* cst   = ws + OFF_CST;
    float* lossp = ws + OFF_LP;
    int*   stamps = (int*)(ws + OFF_STAMP);

    init_bar<<<dim3((STAMP_TOTAL + 255) / 256), dim3(256), 0, stream>>>(stamps);
    to_bf16<<<dim3(2048), dim3(256), 0, stream>>>(Wih, Wihb, 4 * G4n * Dn);
    to_bf16<<<dim3(1024), dim3(256), 0, stream>>>(Whh, Whhb, 4 * G4n * Hn);
    to_bf16<<<dim3(2048), dim3(256), 0, stream>>>(bert, bertb, Bn * Sn * Dn);

    #define GBUF(l, c) (gatesb + (size_t)((l) * 2 + ((c) & 1)) * BUFU)

    // prologue: gates(0,0)
    gemm_pair<<<dim3(12, 64, 2), dim3(256), 0, stream>>>(
        bertb, 0, 0, GBUF(0, 0), bertb, 0, 0, GBUF(0, 0), 0, Wihb, bvec);

    // stage k: lstm(0,k) || lstm(1,k-1) wave-split; then gemm for (0,k+1) and (1,k)
    for (int k = 0; k <= 8; ++k) {
        int la, ca, lb = 1, cb = k - 1;
        int validB = (k >= 1 && k - 1 <= 7) ? 1 : 0;
        if (k <= 7) { la = 0; ca = k; }
        else       { la = 1; ca = 7; validB = 0; }   // k==8: only lstm(1,7)
        lstm_dual<<<dim3(512), dim3(256), 0, stream>>>(
            GBUF(la, ca), la, ca,
            validB ? GBUF(lb, cb) : GBUF(la, ca), lb, cb, validB,
            Whhb, fcw, h1b, emP, hbuf, cst, stamps);

        if (k <= 6) {
            gemm_pair<<<dim3(12, 64, 2), dim3(256), 0, stream>>>(
                bertb, 0, k + 1, GBUF(0, k + 1),
                h1b, 1, k, GBUF(1, k), 1, Wihb, bvec);
        } else if (k == 7) {
            gemm_pair<<<dim3(12, 64, 2), dim3(256), 0, stream>>>(
                h1b, 1, 7, GBUF(1, 7), h1b, 1, 7, GBUF(1, 7), 0, Wihb, bvec);
        }
    }

    em_combine<<<dim3((Bn * Sn * Tn + 255) / 256), dim3(256), 0, stream>>>(emP, fcb, em);
    crf_loss<<<dim3(Bn), dim3(64), 0, stream>>>(em, y, trans, stt, ent, lossp);
    loss_final<<<dim3(1), dim3(64), 0, stream>>>(lossp, out);
    viterbi_k<<<dim3(Bn), dim3(64), 0, stream>>>(em, trans, stt, ent, out);
}

// Round 15
// 8901.088 us; speedup vs baseline: 3.4442x; 3.4442x over previous
//
#include <hip/hip_runtime.h>

// Problem dims
#define Bn   64
#define Sn   512
#define Dn   768
#define Hn   384
#define G4n  1536   // 4*H
#define Tn   9
#define SCHn 64     // S-chunk
#define NCH  8      // Sn / SCHn

// gates buffer: [dir][b][j][1536] bf16 for one (layer,chunk); 4 buffers (layer x parity)
#define BUFU (2ull * Bn * SCHn * G4n)                     // ushorts per buffer

// ---- workspace layout (in float units) ----
#define OFF_WIHB  0ull
#define SZ_WIHB   (2ull * Dn * G4n)
#define OFF_GATESB (OFF_WIHB + SZ_WIHB)
#define SZ_GATESB (4ull * BUFU / 2)                       // 4 bf16 buffers
#define OFF_H1B   (OFF_GATESB + SZ_GATESB)
#define SZ_H1B    ((unsigned long long)Bn * Sn * Dn / 2)
#define OFF_BERTB (OFF_H1B + SZ_H1B)
#define SZ_BERTB  ((unsigned long long)Bn * Sn * Dn / 2)
#define OFF_EMP   (OFF_BERTB + SZ_BERTB)
#define SZ_EMP    (2ull * Bn * Sn * Tn)
#define OFF_EM    (OFF_EMP + SZ_EMP)
#define SZ_EM     ((unsigned long long)Bn * Sn * Tn)
#define OFF_HBUF  (OFF_EM + SZ_EM)
#define SZ_HBUF   (8ull * Bn * Hn)                        // [L][parity][dir][b][d]
#define OFF_CST   (OFF_HBUF + SZ_HBUF)
#define SZ_CST    (4ull * Bn * Hn)                        // [L][dir][b][d]
#define OFF_LP    (OFF_CST + SZ_CST)
#define SZ_LP     64ull
#define OFF_STAMP (OFF_LP + SZ_LP)
// stamps: [L:2][dir:2][bg:8][dg:32] lines of 32 ints; tag = sg+1 (per-layer region)
#define STAMP_TOTAL (2 * 2 * 8 * 32 * 32)

typedef __attribute__((ext_vector_type(8))) short short8v;
typedef __attribute__((ext_vector_type(4))) float f32x4;

static __device__ __forceinline__ float sigf(float x) { return 1.f / (1.f + expf(-x)); }

static __device__ __forceinline__ unsigned short f2bf(float x) {
    unsigned u = __float_as_uint(x);
    u += 0x7fffu + ((u >> 16) & 1u);   // RNE
    return (unsigned short)(u >> 16);
}
static __device__ __forceinline__ float bf2f(unsigned short u) {
    return __uint_as_float(((unsigned)u) << 16);
}

// ---- LLC primitives: relaxed system scope ----
static __device__ __forceinline__ unsigned long long llc_load_u64(const unsigned long long* p) {
    return __hip_atomic_load(p, __ATOMIC_RELAXED, __HIP_MEMORY_SCOPE_SYSTEM);
}
static __device__ __forceinline__ void llc_store_f32(float* p, float v) {
    __hip_atomic_store(p, v, __ATOMIC_RELAXED, __HIP_MEMORY_SCOPE_SYSTEM);
}
static __device__ __forceinline__ int llc_load_i32(const int* p) {
    return __hip_atomic_load(p, __ATOMIC_RELAXED, __HIP_MEMORY_SCOPE_SYSTEM);
}

// ---------------- fp32 -> bf16 convert ----------------
__global__ void to_bf16(const float* __restrict__ in, unsigned short* __restrict__ out,
                        int total)
{
    for (int i = blockIdx.x * 256 + threadIdx.x; i < total; i += gridDim.x * 256)
        out[i] = f2bf(in[i]);
}

// ---------------- stamp init (every launch: replay-safe) ----------------
__global__ void init_bar(int* __restrict__ st)
{
    const int i = blockIdx.x * 256 + threadIdx.x;
    if (i < STAMP_TOTAL) st[i] = 0;
}

// ---------------- gemm tile body (bf16 in/out, MFMA) ----------------
// G[m][col'] = A_row(m) . Wih^T[:,n] + b[n]; col' = (n%384)*4 + n/384.
// Tile 128x128, BK=32, 4 waves of 64x64. SCHn=64 row mapping.
static __device__ __forceinline__ void gemm_tile(
    unsigned short As[][40], unsigned short Bs[][40],
    const unsigned short* __restrict__ Abf,
    const unsigned short* __restrict__ Wb,
    const float* __restrict__ bvec,
    unsigned short* __restrict__ G,
    int layer, int chunk, int nb, int mb, int tid)
{
    const int m0  = mb * 128;
    const int dir = mb >> 5;          // 32 tiles (4096 rows) per dir
    const int n0c = nb * 128;

    const unsigned short* BT = Wb + (size_t)(layer * 2 + dir) * G4n * Dn;
    const float* bias = bvec + (size_t)(layer * 2 + dir) * G4n;

    const int mm   = tid >> 1;
    const int seg  = (tid & 1) * 16;
    const int rem  = (m0 + mm) & (Bn * SCHn - 1);   // & 4095
    const int bb   = rem >> 6;
    const int j    = rem & (SCHn - 1);
    const int p    = chunk * SCHn + j;
    const int s    = dir ? (Sn - 1 - p) : p;
    const unsigned short* arow = Abf + ((size_t)bb * Sn + s) * Dn;
    const unsigned short* brow = BT + (size_t)(n0c + mm) * Dn;

    const int l = tid & 63, wave = tid >> 6;
    const int wy = wave >> 1, wx = wave & 1;
    const int fr = l & 15, fk = (l >> 4) * 8;

    f32x4 acc[4][4];
    #pragma unroll
    for (int mt = 0; mt < 4; ++mt)
        #pragma unroll
        for (int nt = 0; nt < 4; ++nt)
            acc[mt][nt] = (f32x4){0.f, 0.f, 0.f, 0.f};

    for (int k0 = 0; k0 < Dn; k0 += 32) {
        const short8v a0 = *(const short8v*)(arow + k0 + seg);
        const short8v a1 = *(const short8v*)(arow + k0 + seg + 8);
        const short8v b0 = *(const short8v*)(brow + k0 + seg);
        const short8v b1 = *(const short8v*)(brow + k0 + seg + 8);
        __syncthreads();
        *(short8v*)&As[mm][seg]     = a0;
        *(short8v*)&As[mm][seg + 8] = a1;
        *(short8v*)&Bs[mm][seg]     = b0;
        *(short8v*)&Bs[mm][seg + 8] = b1;
        __syncthreads();

        short8v af[4], bf[4];
        #pragma unroll
        for (int mt = 0; mt < 4; ++mt)
            af[mt] = *(const short8v*)&As[wy * 64 + mt * 16 + fr][fk];
        #pragma unroll
        for (int nt = 0; nt < 4; ++nt)
            bf[nt] = *(const short8v*)&Bs[wx * 64 + nt * 16 + fr][fk];
        #pragma unroll
        for (int mt = 0; mt < 4; ++mt)
            #pragma unroll
            for (int nt = 0; nt < 4; ++nt)
                acc[mt][nt] = __builtin_amdgcn_mfma_f32_16x16x32_bf16(
                    af[mt], bf[nt], acc[mt][nt], 0, 0, 0);
    }

    #pragma unroll
    for (int nt = 0; nt < 4; ++nt) {
        const int n  = n0c + wx * 64 + nt * 16 + fr;
        const int g  = n / 384;
        const int d2 = n - g * 384;
        const int gcol = d2 * 4 + g;
        const float bv = bias[n];
        #pragma unroll
        for (int mt = 0; mt < 4; ++mt) {
            #pragma unroll
            for (int q = 0; q < 4; ++q) {
                const int row = m0 + wy * 64 + mt * 16 + (l >> 4) * 4 + q;
                G[(size_t)row * G4n + gcol] = f2bf(acc[mt][nt][q] + bv);
            }
        }
    }
}

// ---------------- paired gates GEMM (two (layer,chunk) tasks via gridDim.z) ----------------
__global__ __launch_bounds__(256) void gemm_pair(
    const unsigned short* __restrict__ A0, int l0, int c0, unsigned short* __restrict__ G0,
    const unsigned short* __restrict__ A1, int l1, int c1, unsigned short* __restrict__ G1,
    int valid1,
    const unsigned short* __restrict__ Wb, const float* __restrict__ bvec)
{
    __shared__ __align__(16) unsigned short As[128][40];
    __shared__ __align__(16) unsigned short Bs[128][40];
    if (blockIdx.z == 1) {
        if (!valid1) return;
        gemm_tile(As, Bs, A1, Wb, bvec, G1, l1, c1, blockIdx.x, blockIdx.y, threadIdx.x);
    } else {
        gemm_tile(As, Bs, A0, Wb, bvec, G0, l0, c0, blockIdx.x, blockIdx.y, threadIdx.x);
    }
}

// ---------------- dual-layer persistent LSTM recurrence ----------------
// grid 1024 = two 512-halves; half h runs task (layer,chunk) on its own
// stamp/hbuf/cst regions. Per half: (dir:2) x (bg:8 of 8 batches) x (dg:32 of 12 dims).
// Body = round-11 lstm (2 WGs/CU min, VGPR 128, tid0 stamp, 3 barriers).
__global__ __launch_bounds__(256, 2) void lstm_dual(
    const unsigned short* __restrict__ grdA, int la, int ca,
    const unsigned short* __restrict__ grdB, int lb, int cb, int validB,
    const float* __restrict__ Whh,    // [2][2][1536][384]
    const float* __restrict__ fcw,    // [9][768]
    unsigned short* __restrict__ h1b, // [64][512][768] bf16 (layer 0 only)
    float* __restrict__ emP,          // [2][64][512][9] (layer 1 only)
    float* __restrict__ hbuf,         // [L][parity][dir][64][384]
    float* __restrict__ cst,          // [L][dir][64][384]
    int* __restrict__ stamps)
{
    const int tid = threadIdx.x;
    const int bid = blockIdx.x;
    const int half = bid >> 9;
    if (half && !validB) return;
    const unsigned short* grd = half ? grdB : grdA;
    const int layer = half ? lb : la;
    const int chunk = half ? cb : ca;
    const int lbid = bid & 511;
    const int dir = lbid >> 8;
    const int bg  = (lbid >> 5) & 7;
    const int dg  = lbid & 31;
    const int b0 = bg * 8, d0 = dg * 12;

    __shared__ __align__(16) float hstage[8][396];
    __shared__ __align__(16) float red[4][16][28];
    __shared__ float cs[8][12];
    __shared__ float fcwl[Hn];

    const int ct = tid & 15;
    const int kq = tid >> 4;
    const int k0 = kq * 24;
    const int sbb = tid >> 5, skq = tid & 31;
    const bool pw = (tid < 96);
    const int pb = tid / 12, pdd = tid - pb * 12;
    const int lane = tid & 63, wv = tid >> 6;

    int* lstamps = stamps + layer * (2 * 8 * 32 * 32);
    const int* mystamps = lstamps + ((dir * 8 + bg) * 32 + skq) * 32;
    float* lhbuf = hbuf + (size_t)layer * (4ull * Bn * Hn);
    float* lcst  = cst + (size_t)layer * (2ull * Bn * Hn);

    // ---- Whh slice into registers ----
    float wreg[72];
    {
        const float* Wbase = Whh + (size_t)(layer * 2 + dir) * G4n * Hn;
        #pragma unroll
        for (int c = 0; c < 3; ++c) {
            const int cc = ct * 3 + c;               // col' = dd*4+g
            const int dd = cc >> 2, g = cc & 3;
            const float* wr = Wbase + (size_t)(g * Hn + d0 + dd) * Hn + k0;
            #pragma unroll
            for (int kk = 0; kk < 24; kk += 4) {
                const float4 w4 = *(const float4*)(wr + kk);
                wreg[c * 24 + kk + 0] = w4.x;
                wreg[c * 24 + kk + 1] = w4.y;
                wreg[c * 24 + kk + 2] = w4.z;
                wreg[c * 24 + kk + 3] = w4.w;
            }
        }
    }

    const bool fcwg = (layer == 1) && (dg < Tn);
    if (fcwg) {
        for (int k2 = tid; k2 < Hn; k2 += 256)
            fcwl[k2] = fcw[dg * Dn + dir * Hn + k2];
    }

    if (pw) {
        cs[pb][pdd] = (chunk == 0) ? 0.f
            : lcst[((size_t)dir * Bn + b0 + pb) * Hn + d0 + pdd];
    }
    __syncthreads();

    for (int j = 0; j < SCHn; ++j) {
        const int sg = chunk * SCHn + j;
        const int p_rd = sg & 1, p_wr = (sg + 1) & 1;
        const int s = dir ? (Sn - 1 - sg) : sg;

        // input gates for this step (bf16; latency hides under poll/stage)
        float4 g4 = make_float4(0.f, 0.f, 0.f, 0.f);
        if (pw) {
            const ushort4 gu = *(const ushort4*)(grd +
                  (((size_t)(dir * Bn + b0 + pb) * SCHn + j) * G4n) + (d0 + pdd) * 4);
            g4.x = bf2f(gu.x); g4.y = bf2f(gu.y);
            g4.z = bf2f(gu.z); g4.w = bf2f(gu.w);
        }

        // ---- fused per-lane poll + h load + stage ----
        if (chunk == 0 && j == 0) {
            #pragma unroll
            for (int i = 0; i < 6; ++i)
                *(float2*)&hstage[sbb][skq * 12 + 2 * i] = make_float2(0.f, 0.f);
        } else {
            const int need = sg;
            while (llc_load_i32(mystamps) < need) __builtin_amdgcn_s_sleep(1);
            const unsigned long long* hsrc = (const unsigned long long*)
                (lhbuf + ((size_t)(p_rd * 2 + dir) * Bn + b0 + sbb) * Hn) + skq * 6;
            #pragma unroll
            for (int i = 0; i < 6; ++i) {
                const unsigned long long v = llc_load_u64(hsrc + i);
                float2 f2;
                f2.x = __uint_as_float((unsigned int)v);
                f2.y = __uint_as_float((unsigned int)(v >> 32));
                *(float2*)&hstage[sbb][skq * 12 + 2 * i] = f2;
            }
        }
        __syncthreads();   // B: hstage ready

        // ---- recurrent matvec over this thread's k-slice ----
        float acc[24];
        #pragma unroll
        for (int i = 0; i < 24; ++i) acc[i] = 0.f;
        #pragma unroll
        for (int b = 0; b < 8; ++b) {
            const float* hp = &hstage[b][k0];
            float hv[24];
            #pragma unroll
            for (int i = 0; i < 6; ++i) {
                const float4 h4 = *(const float4*)(hp + i * 4);
                hv[i * 4 + 0] = h4.x; hv[i * 4 + 1] = h4.y;
                hv[i * 4 + 2] = h4.z; hv[i * 4 + 3] = h4.w;
            }
            #pragma unroll
            for (int c = 0; c < 3; ++c)
                #pragma unroll
                for (int kk = 0; kk < 24; ++kk)
                    acc[b * 3 + c] += hv[kk] * wreg[c * 24 + kk];
        }
        #pragma unroll
        for (int i = 0; i < 24; ++i) {
            acc[i] += __shfl_xor(acc[i], 16);
            acc[i] += __shfl_xor(acc[i], 32);
        }
        if (lane < 16) {
            #pragma unroll
            for (int i = 0; i < 24; i += 4) {
                float4 t4; t4.x = acc[i]; t4.y = acc[i + 1];
                t4.z = acc[i + 2]; t4.w = acc[i + 3];
                *(float4*)&red[wv][lane][i] = t4;
            }
        }

        // fused FC for step sg-1: hstage holds that step's OUTPUT h
        if (fcwg && j >= 1) {
            const int sgp = sg - 1;
            const int sprev = dir ? (Sn - 1 - sgp) : sgp;
            const float* hp2 = &hstage[sbb][skq * 12];
            const float* wp2 = &fcwl[skq * 12];
            float e2 = 0.f;
            #pragma unroll
            for (int q = 0; q < 12; ++q) e2 += hp2[q] * wp2[q];
            e2 += __shfl_down(e2, 16, 32);
            e2 += __shfl_down(e2, 8, 32);
            e2 += __shfl_down(e2, 4, 32);
            e2 += __shfl_down(e2, 2, 32);
            e2 += __shfl_down(e2, 1, 32);
            if (skq == 0)
                emP[((size_t)(dir * Bn + b0 + sbb) * Sn + sprev) * Tn + dg] = e2;
        }
        __syncthreads();   // C: red ready, hstage readers done

        // ---- final sum + pointwise ----
        if (pw) {
            float pre[4];
            #pragma unroll
            for (int g = 0; g < 4; ++g) {
                const int cc = pdd * 4 + g;
                const int ct2 = cc / 3;
                const int e = pb * 3 + (cc - ct2 * 3);
                pre[g] = red[0][ct2][e] + red[1][ct2][e]
                       + red[2][ct2][e] + red[3][ct2][e];
            }
            const float ii = sigf(pre[0] + g4.x);
            const float ff = sigf(pre[1] + g4.y);
            const float gg = tanhf(pre[2] + g4.z);
            const float oo = sigf(pre[3] + g4.w);
            const float cn = ff * cs[pb][pdd] + ii * gg;
            cs[pb][pdd] = cn;
            const float hn = oo * tanhf(cn);
            llc_store_f32(&lhbuf[((size_t)(p_wr * 2 + dir) * Bn + b0 + pb) * Hn + d0 + pdd], hn);
            if (layer == 0)
                h1b[((size_t)(b0 + pb) * Sn + s) * Dn + dir * Hn + d0 + pdd] = f2bf(hn);
        }
        __syncthreads();   // D: drain stores before stamp
        if (tid == 0)
            __hip_atomic_store(lstamps + ((dir * 8 + bg) * 32 + dg) * 32, sg + 1,
                               __ATOMIC_RELAXED, __HIP_MEMORY_SCOPE_SYSTEM);
    }

    // ---- epilogue: FC for this chunk's last step (layer 1) ----
    if (fcwg) {
        const int sgl = chunk * SCHn + SCHn - 1;
        const int need = sgl + 1;
        while (llc_load_i32(mystamps) < need) __builtin_amdgcn_s_sleep(1);
        const int pp = (sgl + 1) & 1;
        const unsigned long long* hsrc = (const unsigned long long*)
            (lhbuf + ((size_t)(pp * 2 + dir) * Bn + b0 + sbb) * Hn) + skq * 6;
        #pragma unroll
        for (int i = 0; i < 6; ++i) {
            const unsigned long long v = llc_load_u64(hsrc + i);
            float2 f2;
            f2.x = __uint_as_float((unsigned int)v);
            f2.y = __uint_as_float((unsigned int)(v >> 32));
            *(float2*)&hstage[sbb][skq * 12 + 2 * i] = f2;
        }
        __syncthreads();
        const int sprev = dir ? (Sn - 1 - sgl) : sgl;
        const float* hp2 = &hstage[sbb][skq * 12];
        const float* wp2 = &fcwl[skq * 12];
        float e2 = 0.f;
        #pragma unroll
        for (int q = 0; q < 12; ++q) e2 += hp2[q] * wp2[q];
        e2 += __shfl_down(e2, 16, 32);
        e2 += __shfl_down(e2, 8, 32);
        e2 += __shfl_down(e2, 4, 32);
        e2 += __shfl_down(e2, 2, 32);
        e2 += __shfl_down(e2, 1, 32);
        if (skq == 0)
            emP[((size_t)(dir * Bn + b0 + sbb) * Sn + sprev) * Tn + dg] = e2;
    }

    if (pw)
        lcst[((size_t)dir * Bn + b0 + pb) * Hn + d0 + pdd] = cs[pb][pdd];
}

// ---------------- emission combine ----------------
__global__ void em_combine(const float* __restrict__ emP, const float* __restrict__ fcb,
                           float* __restrict__ em)
{
    const int idx = blockIdx.x * 256 + threadIdx.x;
    if (idx < Bn * Sn * Tn) {
        const int t = idx % Tn;
        em[idx] = emP[idx] + emP[(size_t)Bn * Sn * Tn + idx] + fcb[t];
    }
}

// ---------------- CRF negative log-likelihood ----------------
__global__ __launch_bounds__(64) void crf_loss(
    const float* __restrict__ em, const int* __restrict__ y,
    const float* __restrict__ trans, const float* __restrict__ start_t,
    const float* __restrict__ end_t, float* __restrict__ lossp)
{
    const int b = blockIdx.x, tid = threadIdx.x;
    __shared__ float tr[Tn * Tn];
    for (int i = tid; i < Tn * Tn; i += 64) tr[i] = trans[i];
    __syncthreads();
    const int* yb = y + (size_t)b * Sn;
    const float* emb = em + (size_t)b * Sn * Tn;

    float gs = 0.f;
    for (int s2 = tid; s2 < Sn; s2 += 64) gs += emb[s2 * Tn + yb[s2]];
    for (int s2 = tid; s2 < Sn - 1; s2 += 64) gs += tr[yb[s2] * Tn + yb[s2 + 1]];
    #pragma unroll
    for (int o = 32; o > 0; o >>= 1) gs += __shfl_down(gs, o, 64);

    const int jj = (tid < Tn) ? tid : 0;
    float alpha = start_t[jj] + emb[jj];
    for (int s2 = 1; s2 < Sn; ++s2) {
        float av[Tn];
        #pragma unroll
        for (int i = 0; i < Tn; ++i) av[i] = __shfl(alpha, i, 64) + tr[i * Tn + jj];
        float m = av[0];
        #pragma unroll
        for (int i = 1; i < Tn; ++i) m = fmaxf(m, av[i]);
        float ss = 0.f;
        #pragma unroll
        for (int i = 0; i < Tn; ++i) ss += expf(av[i] - m);
        alpha = logf(ss) + m + emb[s2 * Tn + jj];
    }
    const float xv = alpha + end_t[jj];
    float m9 = -1e30f, vv[Tn];
    #pragma unroll
    for (int i = 0; i < Tn; ++i) { vv[i] = __shfl(xv, i, 64); m9 = fmaxf(m9, vv[i]); }
    float s9 = 0.f;
    #pragma unroll
    for (int i = 0; i < Tn; ++i) s9 += expf(vv[i] - m9);
    const float logZ = logf(s9) + m9;
    if (tid == 0) lossp[b] = logZ - (gs + start_t[yb[0]] + end_t[yb[Sn - 1]]);
}

__global__ __launch_bounds__(64) void loss_final(const float* __restrict__ lossp,
                                                 float* __restrict__ out)
{
    float v = lossp[threadIdx.x];
    #pragma unroll
    for (int o = 32; o > 0; o >>= 1) v += __shfl_down(v, o, 64);
    if (threadIdx.x == 0) out[0] = v * (1.f / 64.f);
}

// ---------------- Viterbi decode ----------------
__global__ __launch_bounds__(64) void viterbi_k(
    const float* __restrict__ em, const float* __restrict__ trans,
    const float* __restrict__ start_t, const float* __restrict__ end_t,
    float* __restrict__ out)
{
    const int b = blockIdx.x, tid = threadIdx.x;
    __shared__ float tr[Tn * Tn];
    __shared__ unsigned char bp[Sn - 1][16];
    __shared__ float vfin[Tn];
    for (int i = tid; i < Tn * Tn; i += 64) tr[i] = trans[i];
    __syncthreads();
    const float* emb = em + (size_t)b * Sn * Tn;
    const int jj = (tid < Tn) ? tid : 0;
    float v = start_t[jj] + emb[jj];
    for (int s2 = 1; s2 < Sn; ++s2) {
        float vv[Tn];
        #pragma unroll
        for (int i = 0; i < Tn; ++i) vv[i] = __shfl(v, i, 64);
        float best = -1e30f; int bi = 0;
        #pragma unroll
        for (int i = 0; i < Tn; ++i) {
            const float sc = vv[i] + tr[i * Tn + jj];
            if (sc > best) { best = sc; bi = i; }   // strict > == first-max (np.argmax)
        }
        if (tid < Tn) bp[s2 - 1][tid] = (unsigned char)bi;
        v = best + emb[s2 * Tn + jj];
    }
    if (tid < Tn) vfin[tid] = v + end_t[tid];
    __syncthreads();
    if (tid == 0) {
        float best = -1e30f; int cur = 0;
        for (int i = 0; i < Tn; ++i) if (vfin[i] > best) { best = vfin[i]; cur = i; }
        float* ob = out + 1 + (size_t)b * Sn;
        ob[Sn - 1] = (float)cur;
        for (int s2 = Sn - 1; s2 >= 1; --s2) { cur = bp[s2 - 1][cur]; ob[s2 - 1] = (float)cur; }
    }
}

// ---------------- launch ----------------
extern "C" void kernel_launch(void* const* d_in, const int* in_sizes, int n_in,
                              void* d_out, int out_size, void* d_ws, size_t ws_size,
                              hipStream_t stream)
{
    (void)in_sizes; (void)n_in; (void)out_size; (void)ws_size;
    const float* bert  = (const float*)d_in[0];
    const int*   y     = (const int*)d_in[1];
    const float* Wih   = (const float*)d_in[2];
    const float* Whh   = (const float*)d_in[3];
    const float* bvec  = (const float*)d_in[4];
    const float* fcw   = (const float*)d_in[5];
    const float* fcb   = (const float*)d_in[6];
    const float* trans = (const float*)d_in[7];
    const float* stt   = (const float*)d_in[8];
    const float* ent   = (const float*)d_in[9];
    float* out = (float*)d_out;
    float* ws  = (float*)d_ws;

    unsigned short* Wihb   = (unsigned short*)(ws + OFF_WIHB);
    unsigned short* gatesb = (unsigned short*)(ws + OFF_GATESB);
    unsigned short* h1b    = (unsigned short*)(ws + OFF_H1B);
    unsigned short* bertb  = (unsigned short*)(ws + OFF_BERTB);
    float* emP   = ws + OFF_EMP;
    float* em    = ws + OFF_EM;
    float* hbuf  = ws + OFF_HBUF;
    float* cst   = ws + OFF_CST;
    float* lossp = ws + OFF_LP;
    int*   stamps = (int*)(ws + OFF_STAMP);

    init_bar<<<dim3((STAMP_TOTAL + 255) / 256), dim3(256), 0, stream>>>(stamps);
    to_bf16<<<dim3(2048), dim3(256), 0, stream>>>(Wih, Wihb, 4 * G4n * Dn);
    to_bf16<<<dim3(2048), dim3(256), 0, stream>>>(bert, bertb, Bn * Sn * Dn);

    #define GBUF(l, c) (gatesb + (size_t)((l) * 2 + ((c) & 1)) * BUFU)

    // prologue: gates(0,0)
    gemm_pair<<<dim3(12, 64, 2), dim3(256), 0, stream>>>(
        bertb, 0, 0, GBUF(0, 0), bertb, 0, 0, GBUF(0, 0), 0, Wihb, bvec);

    // stage k: lstm(0,k) || lstm(1,k-1); then gemm for (0,k+1) and (1,k)
    for (int k = 0; k <= 8; ++k) {
        int la, ca, lb = 1, cb = k - 1;
        int validB = (k >= 1 && k - 1 <= 7) ? 1 : 0;
        if (k <= 7) { la = 0; ca = k; }
        else       { la = 1; ca = 7; validB = 0; }   // k==8: only lstm(1,7)
        lstm_dual<<<dim3(1024), dim3(256), 0, stream>>>(
            GBUF(la, ca), la, ca,
            validB ? GBUF(lb, cb) : GBUF(la, ca), lb, cb, validB,
            Whh, fcw, h1b, emP, hbuf, cst, stamps);

        if (k <= 6) {
            gemm_pair<<<dim3(12, 64, 2), dim3(256), 0, stream>>>(
                bertb, 0, k + 1, GBUF(0, k + 1),
                h1b, 1, k, GBUF(1, k), 1, Wihb, bvec);
        } else if (k == 7) {
            gemm_pair<<<dim3(12, 64, 2), dim3(256), 0, stream>>>(
                h1b, 1, 7, GBUF(1, 7), h1b, 1, 7, GBUF(1, 7), 0, Wihb, bvec);
        }
    }

    em_combine<<<dim3((Bn * Sn * Tn + 255) / 256), dim3(256), 0, stream>>>(emP, fcb, em);
    crf_loss<<<dim3(Bn), dim3(64), 0, stream>>>(em, y, trans, stt, ent, lossp);
    loss_final<<<dim3(1), dim3(64), 0, stream>>>(lossp, out);
    viterbi_k<<<dim3(Bn), dim3(64), 0, stream>>>(em, trans, stt, ent, out);
}